// Round 4
// baseline (645.291 us; speedup 1.0000x reference)
//
#include <hip/hip_runtime.h>
#include <stdint.h>

#define T_TOK 8192
#define HDIM  2048
#define NEXP  8
#define TILE  128
#define BK    64            // k-elems per LDS tile; 8 chunks of 8 bf16 per row
#define RTOK  32            // tokens per router block
#define PADGRID 17408       // >= 2*T_TOK + NEXP*(TILE-1) = 17400

typedef __bf16 bf16x8 __attribute__((ext_vector_type(8)));
typedef float  f32x4  __attribute__((ext_vector_type(4)));
typedef unsigned short u16;
typedef u16    u16x8  __attribute__((ext_vector_type(8)));

typedef const __attribute__((address_space(1))) void* gptr_t;
typedef __attribute__((address_space(3))) void* lptr_t;

static __device__ __forceinline__ u16 f2bf(float f) {
    union { float f; unsigned u; } v; v.f = f;
    unsigned u = v.u;
    u = (u + 0x7FFFu + ((u >> 16) & 1u)) >> 16;   // RNE
    return (u16)u;
}

// fp32 -> bf16, 8 elems/thread (expert weights)
__global__ __launch_bounds__(256) void cvt_kernel(const float* __restrict__ in,
                                                  u16* __restrict__ out, int n8) {
    int i = blockIdx.x * 256 + threadIdx.x;
    if (i >= n8) return;
    const float4* p = (const float4*)in + (size_t)i * 2;
    float4 a = p[0], b = p[1];
    u16x8 r;
    r[0] = f2bf(a.x); r[1] = f2bf(a.y); r[2] = f2bf(a.z); r[3] = f2bf(a.w);
    r[4] = f2bf(b.x); r[5] = f2bf(b.y); r[6] = f2bf(b.z); r[7] = f2bf(b.w);
    ((u16x8*)out)[i] = r;
}

// Router: 32 tokens/block (4 waves x 8 tokens); logits, top-2, per-block LDS
// lists + 8 global atomics/block. rows[] entries encode token*2 + slot.
__global__ __launch_bounds__(256) void router_kernel(const float* __restrict__ x,
                                                     const float* __restrict__ gw,
                                                     float* __restrict__ logits_out,
                                                     int* __restrict__ cnt,
                                                     int* __restrict__ rows,
                                                     float* __restrict__ wts) {
    __shared__ int   lcnt[NEXP];
    __shared__ int   lbase[NEXP];
    __shared__ int   lrows[NEXP][RTOK];
    __shared__ float lwtsS[NEXP][RTOK];

    int tid  = threadIdx.x;
    int lane = tid & 63;
    int wave = tid >> 6;
    if (tid < NEXP) lcnt[tid] = 0;
    __syncthreads();

    int t0 = blockIdx.x * RTOK + wave * 8;
    const float4* g4 = (const float4*)gw;

    float acc[8][NEXP] = {};
    #pragma unroll
    for (int i = 0; i < HDIM / 4 / 64; i++) {      // 8 iters
        int idx = lane + i * 64;
        float4 gv[NEXP];
        #pragma unroll
        for (int e = 0; e < NEXP; e++) gv[e] = g4[e * (HDIM / 4) + idx];
        #pragma unroll
        for (int tk = 0; tk < 8; tk++) {
            int t = t0 + tk;
            float4 xv = ((const float4*)(x + (size_t)t * HDIM))[idx];
            #pragma unroll
            for (int e = 0; e < NEXP; e++)
                acc[tk][e] += xv.x * gv[e].x + xv.y * gv[e].y +
                              xv.z * gv[e].z + xv.w * gv[e].w;
        }
    }
    #pragma unroll
    for (int tk = 0; tk < 8; tk++)
        #pragma unroll
        for (int e = 0; e < NEXP; e++)
            #pragma unroll
            for (int off = 32; off > 0; off >>= 1)
                acc[tk][e] += __shfl_xor(acc[tk][e], off, 64);

    if (lane == 0) {
        #pragma unroll
        for (int tk = 0; tk < 8; tk++) {
            int t = t0 + tk;
            #pragma unroll
            for (int e = 0; e < NEXP; e++) logits_out[(size_t)t * NEXP + e] = acc[tk][e];
            int e0 = 0;
            #pragma unroll
            for (int e = 1; e < NEXP; e++) if (acc[tk][e] > acc[tk][e0]) e0 = e;
            int e1 = (e0 == 0) ? 1 : 0;
            #pragma unroll
            for (int e = 0; e < NEXP; e++)
                if (e != e0 && acc[tk][e] > acc[tk][e1]) e1 = e;
            float w0 = 1.0f / (1.0f + expf(acc[tk][e1] - acc[tk][e0]));
            int p0 = atomicAdd(&lcnt[e0], 1);
            lrows[e0][p0] = t * 2;     lwtsS[e0][p0] = w0;          // slot 0
            int p1 = atomicAdd(&lcnt[e1], 1);
            lrows[e1][p1] = t * 2 + 1; lwtsS[e1][p1] = 1.0f - w0;   // slot 1
        }
    }
    __syncthreads();
    if (tid < NEXP) lbase[tid] = atomicAdd(&cnt[tid], lcnt[tid]);
    __syncthreads();
    int e = tid >> 5, j = tid & 31;
    if (j < lcnt[e]) {
        int b = lbase[e] + j;
        rows[e * T_TOK + b] = lrows[e][j];
        wts[e * T_TOK + b]  = lwtsS[e][j];
    }
}

// prefix sum of 128-padded expert counts -> ebase[0..8]
__global__ void setup_kernel(const int* __restrict__ cnt, int* __restrict__ ebase) {
    if (threadIdx.x == 0 && blockIdx.x == 0) {
        int s = 0;
        for (int e = 0; e < NEXP; e++) {
            ebase[e] = s;
            s += (cnt[e] + TILE - 1) & ~(TILE - 1);
        }
        ebase[NEXP] = s;
    }
}

// gather+convert: Xg[ebase[e]+r] = bf16(x[token(e,r)]); pad rows -> 0
__global__ __launch_bounds__(256) void pack_kernel(const float* __restrict__ x,
                                                   const int* __restrict__ cnt,
                                                   const int* __restrict__ ebase,
                                                   const int* __restrict__ rows,
                                                   u16* __restrict__ Xg) {
    int j = blockIdx.x;
    if (j >= ebase[NEXP]) return;
    int e = 0;
    #pragma unroll
    for (int k = 1; k < NEXP; k++) if (j >= ebase[k]) e = k;
    int r = j - ebase[e];
    u16x8* dst = (u16x8*)(Xg + (size_t)j * HDIM) + threadIdx.x;
    if (r < cnt[e]) {
        int tok = rows[e * T_TOK + r] >> 1;
        const float4* p = (const float4*)(x + (size_t)tok * HDIM) +
                          (size_t)threadIdx.x * 2;
        float4 a = p[0], b = p[1];
        u16x8 v;
        v[0] = f2bf(a.x); v[1] = f2bf(a.y); v[2] = f2bf(a.z); v[3] = f2bf(a.w);
        v[4] = f2bf(b.x); v[5] = f2bf(b.y); v[6] = f2bf(b.z); v[7] = f2bf(b.w);
        *dst = v;
    } else {
        u16x8 z = {};
        *dst = z;
    }
}

// grouped GEMM, m97 structure + XCD swizzle; A now CONTIGUOUS from Xg
// (no gather in the K-loop — only the epilogue scatter uses rows/wts).
__global__ __launch_bounds__(256) void moe_gemm(const u16* __restrict__ Xg,
                                                const u16* __restrict__ wb,
                                                const int* __restrict__ cnt,
                                                const int* __restrict__ ebase,
                                                const int* __restrict__ rows,
                                                const float* __restrict__ wts,
                                                float* __restrict__ out) {
    int p  = blockIdx.x;
    int xc = p & 7;
    int q  = p >> 3;
    int rt = q & 63;
    int g  = (q >> 6) * 8 + xc;      // 0..127 = expert*16 + coltile
    int e  = g >> 4;
    int nb = (g & 15) * TILE;

    int count = cnt[e];
    int rowBase = rt * TILE;
    if (rowBase >= count) return;

    const u16*   W     = wb  + (size_t)e * HDIM * HDIM;
    const int*   rlist = rows + e * T_TOK;
    const float* wlist = wts  + e * T_TOK;
    const u16*   Abase = Xg + (size_t)(ebase[e] + rowBase) * HDIM;

    __shared__ u16 As[TILE * BK];   // 16 KB
    __shared__ u16 Bs[TILE * BK];   // 16 KB

    int tid  = threadIdx.x;
    int lane = tid & 63;
    int wave = tid >> 6;
    int wr = wave >> 1, wc = wave & 1;

    // staging: thread tid stages slot (pp*256 + tid); row = slot>>3,
    // stored chunk = slot&7, logical chunk = (slot&7)^(row&7)
    const u16* a_src[4];
    const u16* b_src[4];
    #pragma unroll
    for (int pp = 0; pp < 4; pp++) {
        int row  = (tid >> 3) + pp * 32;            // 0..127
        int clog = (tid & 7) ^ (row & 7);
        a_src[pp] = Abase + (size_t)row * HDIM + clog * 8;
        b_src[pp] = W + (size_t)(nb + row) * HDIM + clog * 8;
    }
    int wslot = (tid & ~63);                        // wave-uniform
    u16* lds_a[4]; u16* lds_b[4];
    #pragma unroll
    for (int pp = 0; pp < 4; pp++) {
        lds_a[pp] = As + (size_t)(pp * 256 + wslot) * 8;
        lds_b[pp] = Bs + (size_t)(pp * 256 + wslot) * 8;
    }

    int lrow = lane & 15;
    int kq   = lane >> 4;
    int mloc[4], nloc[4];
    #pragma unroll
    for (int i = 0; i < 4; i++) {
        mloc[i] = wr * 64 + i * 16 + lrow;
        nloc[i] = wc * 64 + i * 16 + lrow;
    }

    f32x4 acc[4][4] = {};

    for (int kb = 0; kb < HDIM; kb += BK) {
        __syncthreads();
        #pragma unroll
        for (int pp = 0; pp < 4; pp++) {
            __builtin_amdgcn_global_load_lds((gptr_t)(a_src[pp] + kb),
                                             (lptr_t)lds_a[pp], 16, 0, 0);
            __builtin_amdgcn_global_load_lds((gptr_t)(b_src[pp] + kb),
                                             (lptr_t)lds_b[pp], 16, 0, 0);
        }
        __syncthreads();

        #pragma unroll
        for (int s = 0; s < 2; s++) {
            int chunk = s * 4 + kq;
            bf16x8 a[4], b[4];
            #pragma unroll
            for (int i = 0; i < 4; i++) {
                int aslot = (mloc[i] << 3) | (chunk ^ (mloc[i] & 7));
                int bslot = (nloc[i] << 3) | (chunk ^ (nloc[i] & 7));
                a[i] = *(const bf16x8*)(As + aslot * 8);
                b[i] = *(const bf16x8*)(Bs + bslot * 8);
            }
            #pragma unroll
            for (int mt = 0; mt < 4; mt++)
                #pragma unroll
                for (int nt = 0; nt < 4; nt++)
                    acc[mt][nt] = __builtin_amdgcn_mfma_f32_16x16x32_bf16(
                                      a[mt], b[nt], acc[mt][nt], 0, 0, 0);
        }
    }

    int srow = (lane >> 4) * 4;
    #pragma unroll
    for (int mt = 0; mt < 4; mt++) {
        #pragma unroll
        for (int r = 0; r < 4; r++) {
            int row = rowBase + wr * 64 + mt * 16 + srow + r;
            if (row < count) {
                int   tok = rlist[row] >> 1;
                float wgt = wlist[row];
                #pragma unroll
                for (int nt = 0; nt < 4; nt++) {
                    int col = nb + wc * 64 + nt * 16 + lrow;
                    atomicAdd(out + (size_t)tok * HDIM + col, wgt * acc[mt][nt][r]);
                }
            }
        }
    }
}

extern "C" void kernel_launch(void* const* d_in, const int* in_sizes, int n_in,
                              void* d_out, int out_size, void* d_ws, size_t ws_size,
                              hipStream_t stream) {
    const float* x  = (const float*)d_in[0];   // [T, H]
    const float* gw = (const float*)d_in[1];   // [E, H]
    const float* ew = (const float*)d_in[2];   // [E, H, H]
    float* out    = (float*)d_out;             // [T, H] fp32
    float* logits = out + (size_t)T_TOK * HDIM;

    char* ws = (char*)d_ws;
    int*   cnt   = (int*)ws;                                  // 32 B
    int*   ebase = (int*)(ws + 128);                          // 36 B
    int*   rows  = (int*)(ws + 1024);                         // 256 KB
    float* wts   = (float*)(ws + 1024 + 262144);              // 256 KB
    u16*   wb    = (u16*)(ws + (1 << 20));                    // 64 MB
    u16*   Xg    = wb + (size_t)NEXP * HDIM * HDIM;           // ~68 MB

    hipMemsetAsync(d_out, 0, (size_t)T_TOK * HDIM * sizeof(float), stream);
    hipMemsetAsync(cnt, 0, NEXP * sizeof(int), stream);

    int nw8 = NEXP * HDIM * HDIM / 8;
    cvt_kernel<<<(nw8 + 255) / 256, 256, 0, stream>>>(ew, wb, nw8);

    router_kernel<<<T_TOK / RTOK, 256, 0, stream>>>(x, gw, logits, cnt, rows, wts);

    setup_kernel<<<1, 64, 0, stream>>>(cnt, ebase);

    pack_kernel<<<PADGRID, 256, 0, stream>>>(x, cnt, ebase, rows, Xg);

    moe_gemm<<<NEXP * 64 * 16, 256, 0, stream>>>(Xg, wb, cnt, ebase, rows, wts, out);
}